// Round 5
// baseline (46.909 us; speedup 1.0000x reference)
//
#include <hip/hip_runtime.h>

// loss = (1/N) * sum_over_2x2_blocks [ sum(d^2) - 0.25*(sum d)^2 ],  d = sr - hr
// Derivation: Haar DWT2 is orthonormal; synth-of-one-subband + sum-of-squares
// preserves subband energy; LH^2+HL^2+HH^2 = |d|^2 - LL^2 per block (Parseval).
//
// Single kernel, fence-free completion: each block contributes via ONE 64-bit
// atomicAdd packing {count<<50 | fixed-point partial}. Integer adds commute ->
// bit-deterministic final sum independent of block completion order. The block
// that sees count==BLOCKS-1 converts and writes the scalar. No __threadfence
// (R3 showed 2048 device-scope fences cost 2.7x), no second kernel launch.

static constexpr unsigned long long N_TOTAL = 8ULL * 3ULL * 1024ULL * 1024ULL; // 25,165,824
static constexpr int ROW_W   = 1024;            // image width (floats)
static constexpr int BLOCKS  = 2048;
static constexpr int THREADS = 256;
static constexpr int ITERS   = 6;               // (12288*256) / (2048*256)
static constexpr size_t IT_OFF = (size_t)2048 * 2 * ROW_W;   // 16 MiB in floats
static constexpr double FP_SCALE = 1048576.0;   // 2^20 fixed-point
static constexpr unsigned long long CNT_ONE = 1ULL << 50;
static constexpr unsigned long long VAL_MASK = CNT_ONE - 1ULL;

__global__ __launch_bounds__(256) void whf_fused(const float* __restrict__ sr,
                                                 const float* __restrict__ hr,
                                                 unsigned long long* __restrict__ acc64,
                                                 float* __restrict__ out) {
    const int tid = blockIdx.x * THREADS + threadIdx.x;
    const size_t base = (size_t)(tid >> 8) * (2 * ROW_W) + (size_t)(tid & 255) * 4;

    float4 S0[ITERS], S1[ITERS], H0[ITERS], H1[ITERS];
    #pragma unroll
    for (int it = 0; it < ITERS; ++it) {
        const size_t i0 = base + (size_t)it * IT_OFF;
        S0[it] = *reinterpret_cast<const float4*>(sr + i0);
        S1[it] = *reinterpret_cast<const float4*>(sr + i0 + ROW_W);
        H0[it] = *reinterpret_cast<const float4*>(hr + i0);
        H1[it] = *reinterpret_cast<const float4*>(hr + i0 + ROW_W);
    }

    float acc0 = 0.0f, acc1 = 0.0f;
    #pragma unroll
    for (int it = 0; it < ITERS; ++it) {
        float d00 = S0[it].x - H0[it].x, d01 = S0[it].y - H0[it].y;
        float d10 = S1[it].x - H1[it].x, d11 = S1[it].y - H1[it].y;
        float s = d00 + d01 + d10 + d11;
        float q = d00 * d00 + d01 * d01 + d10 * d10 + d11 * d11;
        acc0 += q - 0.25f * s * s;

        d00 = S0[it].z - H0[it].z; d01 = S0[it].w - H0[it].w;
        d10 = S1[it].z - H1[it].z; d11 = S1[it].w - H1[it].w;
        s = d00 + d01 + d10 + d11;
        q = d00 * d00 + d01 * d01 + d10 * d10 + d11 * d11;
        acc1 += q - 0.25f * s * s;
    }
    float acc = acc0 + acc1;

    // wave64 shuffle reduction
    #pragma unroll
    for (int off = 32; off > 0; off >>= 1)
        acc += __shfl_down(acc, off, 64);

    __shared__ float smem[4];
    const int lane = threadIdx.x & 63;
    const int wid = threadIdx.x >> 6;
    if (lane == 0) smem[wid] = acc;
    __syncthreads();

    if (threadIdx.x == 0) {
        const float p = (smem[0] + smem[1]) + (smem[2] + smem[3]);
        long long v = llrint((double)p * FP_SCALE);
        if (v < 0) v = 0;                         // p >= 0 mathematically; guard fp noise
        const unsigned long long token = CNT_ONE | (unsigned long long)v;
        const unsigned long long old = atomicAdd(acc64, token);
        if ((unsigned int)(old >> 50) == (unsigned int)(BLOCKS - 1)) {
            const unsigned long long total = (old & VAL_MASK) + (unsigned long long)v;
            out[0] = (float)((double)total / (FP_SCALE * (double)N_TOTAL));
        }
    }
}

extern "C" void kernel_launch(void* const* d_in, const int* in_sizes, int n_in,
                              void* d_out, int out_size, void* d_ws, size_t ws_size,
                              hipStream_t stream) {
    const float* sr = (const float*)d_in[0];
    const float* hr = (const float*)d_in[1];
    float* out = (float*)d_out;
    unsigned long long* acc64 = (unsigned long long*)d_ws;

    hipMemsetAsync(acc64, 0, sizeof(unsigned long long), stream);  // capture-safe reset
    whf_fused<<<BLOCKS, THREADS, 0, stream>>>(sr, hr, acc64, out);
}

// Round 6
// 39.209 us; speedup vs baseline: 1.1964x; 1.1964x over previous
//
#include <hip/hip_runtime.h>

// loss = (1/N) * sum_over_2x2_blocks [ sum(d^2) - 0.25*(sum d)^2 ],  d = sr - hr
// Derivation: Haar DWT2 is orthonormal; synth-of-one-subband + sum-of-squares
// preserves subband energy; LH^2+HL^2+HH^2 = |d|^2 - LL^2 per block (Parseval).
//
// Two-kernel structure — both fusion attempts regressed:
//   R3: last-block-done + __threadfence  -> 104 us (2048 device-scope fences = L2 writebacks)
//   R5: packed 64-bit atomic rendezvous  ->  47 us (2048 same-line cross-XCD RMWs serialize)
// A second tiny launch (~3-5 us) is cheaper than any single coherent rendezvous.

static constexpr unsigned long long N_TOTAL = 8ULL * 3ULL * 1024ULL * 1024ULL; // 25,165,824
static constexpr int ROW_W   = 1024;            // image width (floats)
static constexpr int N_ITEMS = 12288 * 256;     // (row-pairs) * (float4 segs per row)
static constexpr int BLOCKS  = 2048;
static constexpr int THREADS = 256;
static constexpr int STRIDE  = BLOCKS * THREADS;   // 524288
static constexpr int ITERS   = N_ITEMS / STRIDE;   // exactly 6
static constexpr size_t IT_OFF = (size_t)2048 * 2 * ROW_W;  // 4,194,304 floats = 16 MiB

__global__ __launch_bounds__(256) void whf_partial(const float* __restrict__ sr,
                                                   const float* __restrict__ hr,
                                                   float* __restrict__ partial) {
    const int tid = blockIdx.x * THREADS + threadIdx.x;
    const size_t base = (size_t)(tid >> 8) * (2 * ROW_W) + (size_t)(tid & 255) * 4;

    float4 S0[ITERS], S1[ITERS], H0[ITERS], H1[ITERS];

    // Issue all 24 loads before any compute: deep memory-level parallelism.
    #pragma unroll
    for (int it = 0; it < ITERS; ++it) {
        const size_t i0 = base + (size_t)it * IT_OFF;
        S0[it] = *reinterpret_cast<const float4*>(sr + i0);
        S1[it] = *reinterpret_cast<const float4*>(sr + i0 + ROW_W);
        H0[it] = *reinterpret_cast<const float4*>(hr + i0);
        H1[it] = *reinterpret_cast<const float4*>(hr + i0 + ROW_W);
    }

    float acc0 = 0.0f, acc1 = 0.0f;
    #pragma unroll
    for (int it = 0; it < ITERS; ++it) {
        // block A: cols {0,1}
        float d00 = S0[it].x - H0[it].x, d01 = S0[it].y - H0[it].y;
        float d10 = S1[it].x - H1[it].x, d11 = S1[it].y - H1[it].y;
        float s = d00 + d01 + d10 + d11;
        float q = d00 * d00 + d01 * d01 + d10 * d10 + d11 * d11;
        acc0 += q - 0.25f * s * s;

        // block B: cols {2,3}
        d00 = S0[it].z - H0[it].z; d01 = S0[it].w - H0[it].w;
        d10 = S1[it].z - H1[it].z; d11 = S1[it].w - H1[it].w;
        s = d00 + d01 + d10 + d11;
        q = d00 * d00 + d01 * d01 + d10 * d10 + d11 * d11;
        acc1 += q - 0.25f * s * s;
    }
    float acc = acc0 + acc1;

    // wave64 shuffle reduction
    #pragma unroll
    for (int off = 32; off > 0; off >>= 1)
        acc += __shfl_down(acc, off, 64);

    __shared__ float smem[4];
    const int lane = threadIdx.x & 63;
    const int wid = threadIdx.x >> 6;
    if (lane == 0) smem[wid] = acc;
    __syncthreads();
    if (threadIdx.x == 0)
        partial[blockIdx.x] = (smem[0] + smem[1]) + (smem[2] + smem[3]);
}

__global__ __launch_bounds__(256) void whf_final(const float* __restrict__ partial,
                                                 float* __restrict__ out) {
    // 256 threads, double accumulation over 2048 partials (deterministic)
    double acc = 0.0;
    for (int i = threadIdx.x; i < BLOCKS; i += 256)
        acc += (double)partial[i];
    #pragma unroll
    for (int off = 32; off > 0; off >>= 1)
        acc += __shfl_down(acc, off, 64);

    __shared__ double smem[4];
    const int lane = threadIdx.x & 63;
    const int wid = threadIdx.x >> 6;
    if (lane == 0) smem[wid] = acc;
    __syncthreads();
    if (threadIdx.x == 0)
        out[0] = (float)(((smem[0] + smem[1]) + (smem[2] + smem[3])) / (double)N_TOTAL);
}

extern "C" void kernel_launch(void* const* d_in, const int* in_sizes, int n_in,
                              void* d_out, int out_size, void* d_ws, size_t ws_size,
                              hipStream_t stream) {
    const float* sr = (const float*)d_in[0];
    const float* hr = (const float*)d_in[1];
    float* out = (float*)d_out;
    float* partial = (float*)d_ws;   // 2048 floats = 8 KiB scratch

    whf_partial<<<BLOCKS, THREADS, 0, stream>>>(sr, hr, partial);
    whf_final<<<1, 256, 0, stream>>>(partial, out);
}